// Round 12
// baseline (337.940 us; speedup 1.0000x reference)
//
#include <hip/hip_runtime.h>
#include <hip/hip_bf16.h>
#include <stdint.h>

typedef unsigned short u16;
typedef u16 u16x4 __attribute__((ext_vector_type(4)));
typedef u16 u16x8 __attribute__((ext_vector_type(8)));
typedef short bf16x8 __attribute__((ext_vector_type(8)));
typedef float f32x4 __attribute__((ext_vector_type(4)));

__device__ __forceinline__ u16 f2bf(float f) {
  union { float f; uint32_t u; } v; v.f = f;
  uint32_t u = v.u;
  return (u16)((u + 0x7fffu + ((u >> 16) & 1u)) >> 16);
}

__device__ __forceinline__ u16x8 cvt8(f32x4 a, f32x4 b) {
  u16x8 o;
  o[0] = f2bf(a.x); o[1] = f2bf(a.y); o[2] = f2bf(a.z); o[3] = f2bf(a.w);
  o[4] = f2bf(b.x); o[5] = f2bf(b.y); o[6] = f2bf(b.z); o[7] = f2bf(b.w);
  return o;
}

// ---------------- aux: W_eff = W + 2*(B@A) -> bf16 (r10 weff, cvt pass DELETED) ----------------
__global__ __launch_bounds__(256) void aux_kernel(
    const float* __restrict__ W, const float* __restrict__ A,
    const float* __restrict__ Bl, u16* __restrict__ Wout, int DIN) {
  const int n0 = (int)blockIdx.x * 4;
  float bv[4][16];
#pragma unroll
  for (int j = 0; j < 4; ++j)
#pragma unroll
    for (int r = 0; r < 16; ++r) bv[j][r] = 2.0f * Bl[(n0 + j) * 16 + r];
  const int iters = DIN / (256 * 4);
  for (int c = 0; c < iters; ++c) {
    const int k = (c * 256 + (int)threadIdx.x) * 4;
    float4 wv[4];
#pragma unroll
    for (int j = 0; j < 4; ++j)
      wv[j] = *(const float4*)&W[(size_t)(n0 + j) * DIN + k];
#pragma unroll
    for (int r = 0; r < 16; ++r) {
      const float4 av = *(const float4*)&A[(size_t)r * DIN + k];
#pragma unroll
      for (int j = 0; j < 4; ++j) {
        wv[j].x += bv[j][r] * av.x;
        wv[j].y += bv[j][r] * av.y;
        wv[j].z += bv[j][r] * av.z;
        wv[j].w += bv[j][r] * av.w;
      }
    }
#pragma unroll
    for (int j = 0; j < 4; ++j) {
      u16x4 o;
      o.x = f2bf(wv[j].x); o.y = f2bf(wv[j].y);
      o.z = f2bf(wv[j].z); o.w = f2bf(wv[j].w);
      *(u16x4*)&Wout[(size_t)(n0 + j) * DIN + k] = o;
    }
  }
}

// ---------------- 256x256 bf16 GEMM, r10 champion schedule; A reg-staged from fp32 x ----------
// C[M][N] = x[M][K](fp32) @ Weff[N][K]^T + bias. 8 waves (2M x 4N), wave out 128x64.
// LDS image, swizzle, read path, phases, gates, barriers = r10 champion verbatim.
// A staging: 4x global_load_dwordx4 fp32 -> RNE pack bf16 -> 2x ds_write_b128 (same
// LDS bytes the DMA wrote). B staging: DMA global_load_lds (unchanged).
// vmcnt FIFO/chunk: ph0 LA4, ph1 DB2, ph2 LA4, ph3 DB2. Waits: vmcnt(2)@ph0/ph2
// (retire the LA quad), vmcnt(6)@ph1/ph3 gates (retire the B slab) + lgkmcnt(0)
// publishing ds_writes before each gate BAR. Issue groups pinned by PIN() fences.
#define BM 256
#define BN 256

__global__ __launch_bounds__(512, 2) void gemm256_kernel(
    const float* __restrict__ X, const u16* __restrict__ B,
    const float* __restrict__ bias, float* __restrict__ C,
    int M, int N, int K) {
  extern __shared__ u16 lds[];   // 131072 bytes

  const int tid  = threadIdx.x;
  const int lane = tid & 63;
  const int wid  = tid >> 6;

  const int nwg = gridDim.x;
  const int cpx = nwg >> 3;
  const int f   = ((int)blockIdx.x & 7) * cpx + ((int)blockIdx.x >> 3);
  const int nbx = N / BN;
  const int bx = f % nbx, by = f / nbx;
  const int bm = by * BM, bn = bx * BN;

  const int wmL = (wid >> 2) * 128;
  const int wnL = (wid & 3) * 64;
  const int lr  = lane & 15;
  const int lk  = lane >> 4;
  const int rslot = ((lk ^ ((lr >> 1) & 3)) << 3);

  const int srow  = tid >> 2;
  const int sslot = (((tid & 3) ^ ((tid >> 3) & 3)) << 3);
  const float* gX = X + (size_t)(bm + srow) * K + sslot;   // fp32 source, same swizzle
  const u16*  gB = B + (size_t)(bn + srow) * K + sslot;

#define PIN() asm volatile("" ::: "memory")

  // A: issue 4 fp32 dwordx4 (2 rows x 2 half-granules), k-sub ks of chunk kt
  auto issueA = [&](int kt, int ks, f32x4* r) {
    const float* s = gX + kt * 64 + ks * 32;
    r[0] = *(const f32x4*)(s);
    r[1] = *(const f32x4*)(s + 4);
    r[2] = *(const f32x4*)(s + (size_t)128 * K);
    r[3] = *(const f32x4*)(s + (size_t)128 * K + 4);
  };
  // pack + ds_write into the exact bytes the champion DMA wrote
  auto writeA = [&](int par, int ks, const f32x4* r) {
    *(u16x8*)&lds[(par * 2 + ks) * 8192 + tid * 8]        = cvt8(r[0], r[1]);
    *(u16x8*)&lds[(par * 2 + ks) * 8192 + 4096 + tid * 8] = cvt8(r[2], r[3]);
  };
  auto stageB = [&](int par, int ks, int kt) {
    u16* d = &lds[32768 + (par * 2 + ks) * 8192 + wid * 512];
    const u16* s = gB + kt * 64 + ks * 32;
#pragma unroll
    for (int i = 0; i < 2; ++i)
      __builtin_amdgcn_global_load_lds(
          (__attribute__((address_space(1))) const void*)(s + (size_t)i * 128 * K),
          (__attribute__((address_space(3))) void*)(d + i * 4096), 16, 0, 0);
  };

  auto ldA = [&](int par, int ks, int mf) -> bf16x8 {
    return *(const bf16x8*)&lds[(par * 2 + ks) * 8192 + (wmL + mf * 16 + lr) * 32 + rslot];
  };
  auto ldB = [&](int par, int ks, int nf) -> bf16x8 {
    return *(const bf16x8*)&lds[32768 + (par * 2 + ks) * 8192 + (wnL + nf * 16 + lr) * 32 + rslot];
  };

  f32x4 acc[8][4];
#pragma unroll
  for (int i = 0; i < 8; ++i)
#pragma unroll
    for (int n = 0; n < 4; ++n) acc[i][n] = f32x4{0.f, 0.f, 0.f, 0.f};

#define VM2()   asm volatile("s_waitcnt vmcnt(2)" ::: "memory")
#define VM6()   asm volatile("s_waitcnt vmcnt(6)" ::: "memory")
#define LGKM0() asm volatile("s_waitcnt lgkmcnt(0)" ::: "memory")
#define BAR()   __builtin_amdgcn_s_barrier()

  const int NT = K >> 6;
  f32x4 rA0[4], rA1[4];

  // prologue: queue = LA0(0)4, DB0(0)2, LA1(0)4, DB1(0)2  (12 ops)
  issueA(0, 0, rA0); PIN();
  stageB(0, 0, 0);   PIN();
  issueA(0, 1, rA1); PIN();
  stageB(0, 1, 0);   PIN();
  VM6();                     // retires LA0(0), DB0(0)
  writeA(0, 0, rA0);         // A(0,0) -> LDS
  LGKM0(); BAR();

  bf16x8 aE[4], aO[4], b0[4], b1[4];
#pragma unroll
  for (int n = 0; n < 4; ++n) b0[n] = ldB(0, 0, n);
#pragma unroll
  for (int m = 0; m < 4; ++m) aE[m] = ldA(0, 0, m);

  for (int t = 0; t < NT; ++t) {
    const int par = t & 1, npar = par ^ 1;
    const int tn = (t + 1 < NT) ? t + 1 : 0;   // wrap keeps vmcnt count uniform

    // ---- phase 0: write A(t,ks1); issue LA(t+1,ks0); consume (aE,b0); prefetch aO ----
    VM2();                       // retires LA1(t) quad (rA1 ready)
    writeA(par, 1, rA1);         // A(t,1) -> LDS (readers gated at ph1 LGKM0+BAR)
    PIN();
    issueA(tn, 0, rA0); PIN();
#pragma unroll
    for (int m = 0; m < 4; ++m) aO[m] = ldA(par, 0, 4 + m);
    __builtin_amdgcn_s_setprio(1);
#pragma unroll
    for (int m = 0; m < 4; ++m)
#pragma unroll
      for (int n = 0; n < 4; ++n)
        acc[m][n] = __builtin_amdgcn_mfma_f32_16x16x32_bf16(aE[m], b0[n], acc[m][n], 0, 0, 0);
    __builtin_amdgcn_s_setprio(0);

    // ---- phase 1: stage B(t+1,0); gate B(t,1); prefetch (b1,aE)=ks1; MFMA(aO,b0) ----
    stageB(npar, 0, tn); PIN();
    VM6();                       // retires DB1(t): B(t,1) resident
    LGKM0();                     // publish writeA(par,1)
    BAR();
#pragma unroll
    for (int n = 0; n < 4; ++n) b1[n] = ldB(par, 1, n);
#pragma unroll
    for (int m = 0; m < 4; ++m) aE[m] = ldA(par, 1, m);
    __builtin_amdgcn_s_setprio(1);
#pragma unroll
    for (int m = 0; m < 4; ++m)
#pragma unroll
      for (int n = 0; n < 4; ++n)
        acc[4 + m][n] = __builtin_amdgcn_mfma_f32_16x16x32_bf16(aO[m], b0[n], acc[4 + m][n], 0, 0, 0);
    __builtin_amdgcn_s_setprio(0);

    // ---- phase 2: write A(t+1,0); issue LA(t+1,ks1); consume (aE,b1); prefetch aO ----
    VM2();                       // retires LA0(t+1) quad (rA0 ready)
    writeA(npar, 0, rA0);        // A(t+1,0) -> LDS (readers gated at ph3 LGKM0+BAR)
    PIN();
    issueA(tn, 1, rA1); PIN();
#pragma unroll
    for (int m = 0; m < 4; ++m) aO[m] = ldA(par, 1, 4 + m);
    __builtin_amdgcn_s_setprio(1);
#pragma unroll
    for (int m = 0; m < 4; ++m)
#pragma unroll
      for (int n = 0; n < 4; ++n)
        acc[m][n] = __builtin_amdgcn_mfma_f32_16x16x32_bf16(aE[m], b1[n], acc[m][n], 0, 0, 0);
    __builtin_amdgcn_s_setprio(0);

    // ---- phase 3: stage B(t+1,1); gate B(t+1,0); prefetch (b0,aE)=next ks0; MFMA(aO,b1) ----
    stageB(npar, 1, tn); PIN();
    VM6();                       // retires DB0(t+1): B(t+1,0) resident
    LGKM0();                     // publish writeA(npar,0)
    BAR();
#pragma unroll
    for (int n = 0; n < 4; ++n) b0[n] = ldB(npar, 0, n);
#pragma unroll
    for (int m = 0; m < 4; ++m) aE[m] = ldA(npar, 0, m);
    __builtin_amdgcn_s_setprio(1);
#pragma unroll
    for (int m = 0; m < 4; ++m)
#pragma unroll
      for (int n = 0; n < 4; ++n)
        acc[4 + m][n] = __builtin_amdgcn_mfma_f32_16x16x32_bf16(aO[m], b1[n], acc[4 + m][n], 0, 0, 0);
    __builtin_amdgcn_s_setprio(0);
  }

  // drain wrapped staging ops before LDS dealloc / kernel end
  asm volatile("s_waitcnt vmcnt(0)" ::: "memory");
  __builtin_amdgcn_s_barrier();

  // epilogue: C/D layout col = lane&15, row = (lane>>4)*4 + j
#pragma unroll
  for (int nf = 0; nf < 4; ++nf) {
    const int col = bn + wnL + nf * 16 + lr;
    const float bv = bias[col];
#pragma unroll
    for (int mf = 0; mf < 8; ++mf) {
      const int row = bm + wmL + mf * 16 + lk * 4;
#pragma unroll
      for (int j = 0; j < 4; ++j)
        C[(size_t)(row + j) * N + col] = acc[mf][nf][j] + bv;
    }
  }
#undef PIN
#undef VM2
#undef VM6
#undef LGKM0
#undef BAR
}

extern "C" void kernel_launch(void* const* d_in, const int* in_sizes, int n_in,
                              void* d_out, int out_size, void* d_ws, size_t ws_size,
                              hipStream_t stream) {
  const float* x  = (const float*)d_in[0];
  const float* w  = (const float*)d_in[1];
  const float* lA = (const float*)d_in[2];
  const float* lB = (const float*)d_in[3];
  const float* bs = (const float*)d_in[4];
  float* out = (float*)d_out;

  const int DOUT = in_sizes[4];              // 4096
  const int DIN  = in_sizes[1] / DOUT;       // 4096
  const int M    = in_sizes[0] / DIN;        // 8192

  u16* Wb = (u16*)d_ws;                      // DOUT*DIN bf16

  aux_kernel<<<DOUT / 4, 256, 0, stream>>>(w, lA, lB, Wb, DIN);

  (void)hipFuncSetAttribute((const void*)gemm256_kernel,
                            hipFuncAttributeMaxDynamicSharedMemorySize, 131072);

  const int nwg = (M / BM) * (DOUT / BN);    // 512
  gemm256_kernel<<<nwg, 512, 131072, stream>>>(x, Wb, bs, out, M, DOUT, DIN);
}

// Round 13
// 313.121 us; speedup vs baseline: 1.0793x; 1.0793x over previous
//
#include <hip/hip_runtime.h>
#include <hip/hip_bf16.h>
#include <stdint.h>

typedef unsigned short u16;
typedef u16 u16x4 __attribute__((ext_vector_type(4)));
typedef short bf16x8 __attribute__((ext_vector_type(8)));
typedef float f32x4 __attribute__((ext_vector_type(4)));

__device__ __forceinline__ u16 f2bf(float f) {
  union { float f; uint32_t u; } v; v.f = f;
  uint32_t u = v.u;
  return (u16)((u + 0x7fffu + ((u >> 16) & 1u)) >> 16);
}

// ---------------- fused aux (r10 champion) ----------------
// blocks [0, nW):        W_eff = W + 2*(B@A) -> bf16, 4 rows/block, r-outer loop
//                        (A loaded once per k-chunk per block; heavy blocks FIRST)
// blocks [nW, nW+nCvt):  x fp32 -> bf16, grid-stride backfill
__global__ __launch_bounds__(256) void aux_kernel(
    const float4* __restrict__ x, u16x4* __restrict__ xb, int n4, int nW, int nCvt,
    const float* __restrict__ W, const float* __restrict__ A,
    const float* __restrict__ Bl, u16* __restrict__ Wout, int DIN) {
  if ((int)blockIdx.x < nW) {
    const int n0 = (int)blockIdx.x * 4;
    float bv[4][16];
#pragma unroll
    for (int j = 0; j < 4; ++j)
#pragma unroll
      for (int r = 0; r < 16; ++r) bv[j][r] = 2.0f * Bl[(n0 + j) * 16 + r];
    const int iters = DIN / (256 * 4);
    for (int c = 0; c < iters; ++c) {
      const int k = (c * 256 + (int)threadIdx.x) * 4;
      float4 wv[4];
#pragma unroll
      for (int j = 0; j < 4; ++j)
        wv[j] = *(const float4*)&W[(size_t)(n0 + j) * DIN + k];
#pragma unroll
      for (int r = 0; r < 16; ++r) {
        const float4 av = *(const float4*)&A[(size_t)r * DIN + k];
#pragma unroll
        for (int j = 0; j < 4; ++j) {
          wv[j].x += bv[j][r] * av.x;
          wv[j].y += bv[j][r] * av.y;
          wv[j].z += bv[j][r] * av.z;
          wv[j].w += bv[j][r] * av.w;
        }
      }
#pragma unroll
      for (int j = 0; j < 4; ++j) {
        u16x4 o;
        o.x = f2bf(wv[j].x); o.y = f2bf(wv[j].y);
        o.z = f2bf(wv[j].z); o.w = f2bf(wv[j].w);
        *(u16x4*)&Wout[(size_t)(n0 + j) * DIN + k] = o;
      }
    }
  } else {
    int i = ((int)blockIdx.x - nW) * 256 + threadIdx.x;
    const int stride = nCvt * 256;
    for (; i < n4; i += stride) {
      float4 v = x[i];
      u16x4 o;
      o.x = f2bf(v.x); o.y = f2bf(v.y); o.z = f2bf(v.z); o.w = f2bf(v.w);
      xb[i] = o;
    }
  }
}

// ---------------- 256x256 deep-pipelined bf16 GEMM (r10 champion) ----------------
// C[M][N] = X[M][K] @ Weff[N][K]^T + bias. 8 waves (2M x 4N), wave out 128x64.
// K-chunk 64 = 2 ks-slabs of 32. LDS 128 KiB: A slabs (par*2+ks)*8192 u16, B at +32768.
// Schedule: 4 phases/chunk, software-pipelined register double-buffer (aE/aO/b0/b1 -
// each phase prefetches the NEXT phase's fragments), exactly 2 gates (vmcnt(4)+barrier)
// per chunk. Swizzled LDS (0 bank conflicts): pre-swizzled global source + swizzled
// read slot (rule #21). Wrap-staging keeps the vmcnt count uniform (never drains - T4).
#define BM 256
#define BN 256

__global__ __launch_bounds__(512, 2) void gemm256_kernel(
    const u16* __restrict__ A, const u16* __restrict__ B,
    const float* __restrict__ bias, float* __restrict__ C,
    int M, int N, int K) {
  extern __shared__ u16 lds[];   // 131072 bytes

  const int tid  = threadIdx.x;
  const int lane = tid & 63;
  const int wid  = tid >> 6;

  // XCD-aware block swizzle (nwg % 8 == 0 by launch)
  const int nwg = gridDim.x;
  const int cpx = nwg >> 3;
  const int f   = ((int)blockIdx.x & 7) * cpx + ((int)blockIdx.x >> 3);
  const int nbx = N / BN;
  const int bx = f % nbx, by = f / nbx;
  const int bm = by * BM, bn = bx * BN;

  const int wmL = (wid >> 2) * 128;
  const int wnL = (wid & 3) * 64;
  const int lr  = lane & 15;
  const int lk  = lane >> 4;
  const int rslot = ((lk ^ ((lr >> 1) & 3)) << 3);  // swizzled k-slot (u16 offset)

  // staging: linear LDS dest, pre-swizzled global source
  const int srow  = tid >> 2;
  const int sslot = (((tid & 3) ^ ((tid >> 3) & 3)) << 3);
  const u16* gA = A + (size_t)(bm + srow) * K + sslot;
  const u16* gB = B + (size_t)(bn + srow) * K + sslot;

  auto stageA = [&](int par, int ks, int kt) {
    u16* d = &lds[(par * 2 + ks) * 8192 + wid * 512];
    const u16* s = gA + kt * 64 + ks * 32;
#pragma unroll
    for (int i = 0; i < 2; ++i)
      __builtin_amdgcn_global_load_lds(
          (__attribute__((address_space(1))) const void*)(s + (size_t)i * 128 * K),
          (__attribute__((address_space(3))) void*)(d + i * 4096), 16, 0, 0);
  };
  auto stageB = [&](int par, int ks, int kt) {
    u16* d = &lds[32768 + (par * 2 + ks) * 8192 + wid * 512];
    const u16* s = gB + kt * 64 + ks * 32;
#pragma unroll
    for (int i = 0; i < 2; ++i)
      __builtin_amdgcn_global_load_lds(
          (__attribute__((address_space(1))) const void*)(s + (size_t)i * 128 * K),
          (__attribute__((address_space(3))) void*)(d + i * 4096), 16, 0, 0);
  };

  auto ldA = [&](int par, int ks, int mf) -> bf16x8 {
    return *(const bf16x8*)&lds[(par * 2 + ks) * 8192 + (wmL + mf * 16 + lr) * 32 + rslot];
  };
  auto ldB = [&](int par, int ks, int nf) -> bf16x8 {
    return *(const bf16x8*)&lds[32768 + (par * 2 + ks) * 8192 + (wnL + nf * 16 + lr) * 32 + rslot];
  };

  f32x4 acc[8][4];
#pragma unroll
  for (int i = 0; i < 8; ++i)
#pragma unroll
    for (int n = 0; n < 4; ++n) acc[i][n] = f32x4{0.f, 0.f, 0.f, 0.f};

  const int NT = K >> 6;
  // prologue: stage chunk 0 fully (A00,B00,A01,B01 = 8 DMA ops)
  stageA(0, 0, 0); stageB(0, 0, 0); stageA(0, 1, 0); stageB(0, 1, 0);
  asm volatile("s_waitcnt vmcnt(4)" ::: "memory");   // A00,B00 resident
  __builtin_amdgcn_s_barrier();

  bf16x8 aE[4], aO[4], b0[4], b1[4];
#pragma unroll
  for (int n = 0; n < 4; ++n) b0[n] = ldB(0, 0, n);
#pragma unroll
  for (int m = 0; m < 4; ++m) aE[m] = ldA(0, 0, m);

#define VM4() asm volatile("s_waitcnt vmcnt(4)" ::: "memory")
#define BAR() __builtin_amdgcn_s_barrier()

  for (int t = 0; t < NT; ++t) {
    const int par = t & 1, npar = par ^ 1;
    const int tn = (t + 1 < NT) ? t + 1 : 0;   // wrap keeps vmcnt count uniform

    // ---- phase 0: consume (aE, b0) = ks0 x m0-3 ; prefetch aO = ks0 m4-7 ----
    stageA(npar, 0, tn);
#pragma unroll
    for (int m = 0; m < 4; ++m) aO[m] = ldA(par, 0, 4 + m);
    __builtin_amdgcn_s_setprio(1);
#pragma unroll
    for (int m = 0; m < 4; ++m)
#pragma unroll
      for (int n = 0; n < 4; ++n)
        acc[m][n] = __builtin_amdgcn_mfma_f32_16x16x32_bf16(aE[m], b0[n], acc[m][n], 0, 0, 0);
    __builtin_amdgcn_s_setprio(0);

    // ---- phase 1: consume (aO, b0) = ks0 x m4-7 ; gate ; prefetch (b1, aE) = ks1 ----
    stageB(npar, 0, tn);
    VM4();   // retires A(par,1), B(par,1) -> ks1 slabs resident
    BAR();
#pragma unroll
    for (int n = 0; n < 4; ++n) b1[n] = ldB(par, 1, n);
#pragma unroll
    for (int m = 0; m < 4; ++m) aE[m] = ldA(par, 1, m);
    __builtin_amdgcn_s_setprio(1);
#pragma unroll
    for (int m = 0; m < 4; ++m)
#pragma unroll
      for (int n = 0; n < 4; ++n)
        acc[4 + m][n] = __builtin_amdgcn_mfma_f32_16x16x32_bf16(aO[m], b0[n], acc[4 + m][n], 0, 0, 0);
    __builtin_amdgcn_s_setprio(0);

    // ---- phase 2: consume (aE, b1) = ks1 x m0-3 ; prefetch aO = ks1 m4-7 ----
    stageA(npar, 1, tn);
#pragma unroll
    for (int m = 0; m < 4; ++m) aO[m] = ldA(par, 1, 4 + m);
    __builtin_amdgcn_s_setprio(1);
#pragma unroll
    for (int m = 0; m < 4; ++m)
#pragma unroll
      for (int n = 0; n < 4; ++n)
        acc[m][n] = __builtin_amdgcn_mfma_f32_16x16x32_bf16(aE[m], b1[n], acc[m][n], 0, 0, 0);
    __builtin_amdgcn_s_setprio(0);

    // ---- phase 3: consume (aO, b1) = ks1 x m4-7 ; gate ; prefetch (b0, aE) = next ks0 ----
    stageB(npar, 1, tn);
    VM4();   // retires A(npar,0), B(npar,0) -> next chunk's ks0 slabs resident
    BAR();
#pragma unroll
    for (int n = 0; n < 4; ++n) b0[n] = ldB(npar, 0, n);
#pragma unroll
    for (int m = 0; m < 4; ++m) aE[m] = ldA(npar, 0, m);
    __builtin_amdgcn_s_setprio(1);
#pragma unroll
    for (int m = 0; m < 4; ++m)
#pragma unroll
      for (int n = 0; n < 4; ++n)
        acc[4 + m][n] = __builtin_amdgcn_mfma_f32_16x16x32_bf16(aO[m], b1[n], acc[4 + m][n], 0, 0, 0);
    __builtin_amdgcn_s_setprio(0);
  }

  // drain wrapped staging DMAs before LDS dealloc / kernel end
  asm volatile("s_waitcnt vmcnt(0)" ::: "memory");
  __builtin_amdgcn_s_barrier();

  // epilogue: C/D layout col = lane&15, row = (lane>>4)*4 + j
#pragma unroll
  for (int nf = 0; nf < 4; ++nf) {
    const int col = bn + wnL + nf * 16 + lr;
    const float bv = bias[col];
#pragma unroll
    for (int mf = 0; mf < 8; ++mf) {
      const int row = bm + wmL + mf * 16 + lk * 4;
#pragma unroll
      for (int j = 0; j < 4; ++j)
        C[(size_t)(row + j) * N + col] = acc[mf][nf][j] + bv;
    }
  }
#undef VM4
#undef BAR
}

extern "C" void kernel_launch(void* const* d_in, const int* in_sizes, int n_in,
                              void* d_out, int out_size, void* d_ws, size_t ws_size,
                              hipStream_t stream) {
  const float* x  = (const float*)d_in[0];
  const float* w  = (const float*)d_in[1];
  const float* lA = (const float*)d_in[2];
  const float* lB = (const float*)d_in[3];
  const float* bs = (const float*)d_in[4];
  float* out = (float*)d_out;

  const int DOUT = in_sizes[4];              // 4096
  const int DIN  = in_sizes[1] / DOUT;       // 4096
  const int M    = in_sizes[0] / DIN;        // 8192

  u16* Xb = (u16*)d_ws;                      // M*DIN bf16
  u16* Wb = Xb + (size_t)M * DIN;            // DOUT*DIN bf16

  const int n4 = (M * DIN) / 4;
  const int nW   = DOUT / 4;                 // 1024 weff blocks (first)
  const int nCvt = 2048;                     // cvt blocks (backfill)
  aux_kernel<<<nW + nCvt, 256, 0, stream>>>((const float4*)x, (u16x4*)Xb, n4, nW, nCvt,
                                            w, lA, lB, Wb, DIN);

  (void)hipFuncSetAttribute((const void*)gemm256_kernel,
                            hipFuncAttributeMaxDynamicSharedMemorySize, 131072);

  const int nwg = (M / BM) * (DOUT / BN);    // 512
  gemm256_kernel<<<nwg, 512, 131072, stream>>>(Xb, Wb, bs, out, M, DOUT, DIN);
}